// Round 8
// baseline (234.073 us; speedup 1.0000x reference)
//
#include <hip/hip_runtime.h>

typedef float v2f __attribute__((ext_vector_type(2)));

#define HH 192
#define WW 192
#define BATCH 16
#define PLANE (HH*WW)              /* 36864 */
#define NELEM (BATCH*2*PLANE)      /* 1179648 */

// Fused RK2-midpoint STEP kernel (2 RHS evals, 1 launch) via temporal blocking:
// stage u with halo 4; compute rhs1 on the halo-2-extended region (12x100
// sites) -> uh in LDS; compute rhs2 on the 8x96 interior from uh.
// Grid = (2,24,16) = 768 blocks = 3 blocks/CU (the R5 optimum shape).
#define TILEX 96
#define TILEY 8
#define SWW 104  /* TILEX + 8 */
#define SHH 16   /* TILEY + 8 */
#define UHW 100  /* TILEX + 4 */
#define UHH 12   /* TILEY + 4 */
#define NSU (SHH*SWW)   /* 1664 staged u sites */
#define NSH (UHH*UHW)   /* 1200 uh sites */
#define DTF 0.2f
#define DTH 0.1f

// Workspace: [0..200) K8T conv weights (tap-major [25][8]);
// [256..414) PP packed poly weight PAIRS as v2f {k=0,k=1}; bufA/bufB at +512.
//
// PP index map (v2f units):
//  0..11  W0a[i]={pw0[i],pw0[24+i]}      12..23 W0b[i]={pw0[12+i],pw0[36+i]}
//  24 B0a={pb0[0],pb0[2]}  25 B0b={pb0[1],pb0[3]}
//  26..37 W1a[i]={pw1[i],pw1[26+i]}      38..49 W1b[i]={pw1[13+i],pw1[39+i]}
//  50 W112={pw1[12],pw1[38]}  51 W125={pw1[25],pw1[51]}
//  52 B1a={pb1[0],pb1[2]}  53 B1b={pb1[1],pb1[3]}
//  54..67 WF[i]={pwf[i],pwf[14+i]}  (66=WF12, 67=WF13)
//  68 BF={pbf[0],pbf[1]}
//  69,70 GW0a; 71,72 GW0b; 73,74 GW1a; 75,76 GW1b; 77,78 GWF
__global__ void prep_kernel(const float* __restrict__ kern,
                            const float* __restrict__ pw0, const float* __restrict__ pb0,
                            const float* __restrict__ pw1, const float* __restrict__ pb1,
                            const float* __restrict__ pwf, const float* __restrict__ pbf,
                            float* __restrict__ ws)
{
    int t = blockIdx.x * blockDim.x + threadIdx.x;
    if (t < 200) {
        const float inv  = 1.0f / 0.0327249f;
        const float inv2 = inv * inv;
        const float sc[6] = {1.0f, inv, inv, inv2, inv2, inv2};
        int o = t / 8, j = t % 8, dy = o / 5, dx = o % 5;
        float v;
        if (j < 6)       v =  kern[j*25 + dy*5 + dx] * sc[j];
        else if (j == 6) v = -kern[1*25 + dy*5 + (4-dx)] * sc[1];
        else             v = -kern[2*25 + (4-dy)*5 + dx] * sc[2];
        ws[o*8 + j] = v;
    } else if (t < 279) {
        int p = t - 200;
        int arr, a, b;
        if (p < 12)       { arr=0; a=p;      b=24+p; }
        else if (p < 24)  { int i=p-12; arr=0; a=12+i; b=36+i; }
        else if (p == 24) { arr=1; a=0; b=2; }
        else if (p == 25) { arr=1; a=1; b=3; }
        else if (p < 38)  { int i=p-26; arr=2; a=i;    b=26+i; }
        else if (p < 50)  { int i=p-38; arr=2; a=13+i; b=39+i; }
        else if (p == 50) { arr=2; a=12; b=38; }
        else if (p == 51) { arr=2; a=25; b=51; }
        else if (p == 52) { arr=3; a=0; b=2; }
        else if (p == 53) { arr=3; a=1; b=3; }
        else if (p < 68)  { int i=p-54; arr=4; a=i; b=14+i; }
        else if (p == 68) { arr=5; a=0; b=1; }
        else {
            const signed char   A0[10] = {1,2,13,14,1,2,14,15,1,2};
            const signed char   A1[10] = {31,32,43,44,33,34,46,47,21,22};
            const unsigned char AR[10] = {0,0,0,0,2,2,2,2,4,4};
            int i = p - 69; arr = AR[i]; a = A0[i]; b = A1[i];
        }
        const float* bases[6] = {pw0, pb0, pw1, pb1, pwf, pbf};
        v2f v; v[0] = bases[arr][a]; v[1] = bases[arr][b];
        ((v2f*)(ws + 256))[p] = v;
    }
}

// Packed poly (both k in one v2f lane-pair). IN: D2[8] v2f features of one
// site. OUT: res v2f {rhs_k0, rhs_k1}. Identical arithmetic to R5.
__device__ __forceinline__ v2f poly_site(const v2f* __restrict__ PP, const v2f D2[8])
{
#define Z1(i) (D2[(i)%6][(i)/6])
    v2f o0 = PP[24], o1 = PP[25];
    #pragma unroll
    for (int i = 0; i < 12; ++i) {
        const float zv = Z1(i);
        o0 += PP[i]    * zv;
        o1 += PP[12+i] * zv;
    }
    const v2f pb = o0 * o1;
    v2f q0 = PP[52] + PP[50]*pb;
    v2f q1 = PP[53] + PP[51]*pb;
    #pragma unroll
    for (int i = 0; i < 12; ++i) {
        const float zv = Z1(i);
        q0 += PP[26+i] * zv;
        q1 += PP[38+i] * zv;
    }
    const v2f t1 = o1*PP[69] + o0*PP[71];
    const v2f g1 = PP[77] + PP[66]*t1
        + PP[67]*(q1*(PP[73] + PP[50]*t1) + q0*(PP[75] + PP[51]*t1));
    const v2f t2 = o1*PP[70] + o0*PP[72];
    const v2f g2 = PP[78] + PP[66]*t2
        + PP[67]*(q1*(PP[74] + PP[50]*t2) + q0*(PP[76] + PP[51]*t2));

    const float s1 = (g1[0] > 0.0f) ? Z1(1) : D2[6][0];
    const float s2 = (g2[0] > 0.0f) ? Z1(2) : D2[7][0];
    const float s3 = (g1[1] > 0.0f) ? Z1(7) : D2[6][1];
    const float s4 = (g2[1] > 0.0f) ? Z1(8) : D2[7][1];
#define XV1(i) ((i)==1 ? s1 : (i)==2 ? s2 : (i)==7 ? s3 : (i)==8 ? s4 : Z1(i))

    v2f f0 = PP[24], f1 = PP[25];
    #pragma unroll
    for (int i = 0; i < 12; ++i) {
        const float xv = XV1(i);
        f0 += PP[i]    * xv;
        f1 += PP[12+i] * xv;
    }
    const v2f pf = f0 * f1;
    v2f r0 = PP[52] + PP[50]*pf;
    v2f r1 = PP[53] + PP[51]*pf;
    v2f y  = PP[68] + PP[66]*pf;
    #pragma unroll
    for (int i = 0; i < 12; ++i) {
        const float xv = XV1(i);
        r0 += PP[26+i] * xv;
        r1 += PP[38+i] * xv;
        y  += PP[54+i] * xv;
    }
    return y + PP[67]*(r0*r1);
#undef XV1
#undef Z1
}

// One full RK2 midpoint step: uout = u + DT*rhs(u + DT/2*rhs(u)).
__global__ __launch_bounds__(256, 3) void step_kernel(
    const float* __restrict__ uin,
    float* __restrict__ uout,
    const float* __restrict__ ws)
{
    const float* K8T = ws;
    const v2f* PP = (const v2f*)(ws + 256);

    __shared__ v2f shU[SHH][SWW];   // u, halo 4
    __shared__ v2f shH[UHH][UHW];   // uh = u + 0.1*rhs1, halo 2
    const int b   = blockIdx.z;
    const int ty0 = blockIdx.y * TILEY;
    const int tx0 = blockIdx.x * TILEX;
    const int tid = threadIdx.x;
    const size_t bo = (size_t)b * 2 * PLANE;

    // ---- Stage u with halo 4: 1664 sites, 6-7 iters/thread.
    const float* uin_b = uin + bo;
    for (int i = tid; i < NSU; i += 256) {
        const int ly  = i / SWW;
        const int col = i - ly * SWW;
        int gy = ty0 + ly - 4;  if (gy < 0) gy += HH; else if (gy >= HH) gy -= HH;
        int gx = tx0 + col - 4; if (gx < 0) gx += WW; else if (gx >= WW) gx -= WW;
        const int gi = gy*WW + gx;
        v2f v; v[0] = uin_b[gi]; v[1] = uin_b[PLANE + gi];
        shU[ly][col] = v;
    }
    __syncthreads();

    // ---- Eval 1 at ALL 1200 uh sites (incl. halo-2 ring): rhs1 -> uh in LDS.
    // Site (ly,col) is global (ty0-2+ly, tx0-2+col); its 5x5 window is
    // shU[ly..ly+4][col..col+4].
    #pragma unroll 1
    for (int i = tid; i < NSH; i += 256) {
        const int ly  = i / UHW;
        const int col = i - ly * UHW;

        v2f D2[8];
        #pragma unroll
        for (int j = 0; j < 8; ++j) D2[j] = (v2f){0.0f, 0.0f};

        #pragma unroll 1
        for (int dy = 0; dy < 5; ++dy) {
            v2f w0 = shU[ly+dy][col  ];
            v2f w1 = shU[ly+dy][col+1];
            v2f w2 = shU[ly+dy][col+2];
            v2f w3 = shU[ly+dy][col+3];
            v2f w4 = shU[ly+dy][col+4];
            const float* Kt = K8T + dy * 40;
            #pragma unroll
            for (int j = 0; j < 8; ++j) {
                D2[j] += w0 * Kt[j];
                D2[j] += w1 * Kt[8+j];
                D2[j] += w2 * Kt[16+j];
                D2[j] += w3 * Kt[24+j];
                D2[j] += w4 * Kt[32+j];
            }
        }

        const v2f res = poly_site(PP, D2);
        shH[ly][col] = shU[ly+2][col+2] + DTH * res;
    }
    __syncthreads();

    // ---- Eval 2 on the 8x96 interior, 3 px/thread with row sharing.
    const int cy = tid >> 5;            // 0..7
    const int x3 = (tid & 31) * 3;      // 0,3,..,93

    v2f D2a[3][8];
    #pragma unroll
    for (int p = 0; p < 3; ++p)
        #pragma unroll
        for (int j = 0; j < 8; ++j)
            D2a[p][j] = (v2f){0.0f, 0.0f};

    #pragma unroll 1
    for (int dy = 0; dy < 5; ++dy) {
        v2f row[7];
        #pragma unroll
        for (int dx = 0; dx < 7; ++dx)
            row[dx] = shH[cy + dy][x3 + dx];
        const float* Kt = K8T + dy * 40;
        #pragma unroll
        for (int dx = 0; dx < 5; ++dx) {
            #pragma unroll
            for (int j = 0; j < 8; ++j) {
                const float w = Kt[dx*8 + j];
                D2a[0][j] += row[dx]   * w;
                D2a[1][j] += row[dx+1] * w;
                D2a[2][j] += row[dx+2] * w;
            }
        }
    }

    const int oy = ty0 + cy, ox = tx0 + x3;
    const size_t o0i = bo + (size_t)oy * WW + ox;
    #pragma unroll
    for (int p = 0; p < 3; ++p) {
        const v2f res = poly_site(PP, D2a[p]);
        const v2f ub  = shU[cy+4][x3+4+p];     // u_n at the output pixel
        uout[o0i + p]         = ub[0] + DTF * res[0];
        uout[o0i + PLANE + p] = ub[1] + DTF * res[1];
    }
}

extern "C" void kernel_launch(void* const* d_in, const int* in_sizes, int n_in,
                              void* d_out, int out_size, void* d_ws, size_t ws_size,
                              hipStream_t stream)
{
    const float* init = (const float*)d_in[0];
    const float* kern = (const float*)d_in[1];
    const float* pw0  = (const float*)d_in[2];
    const float* pb0  = (const float*)d_in[3];
    const float* pw1  = (const float*)d_in[4];
    const float* pb1  = (const float*)d_in[5];
    const float* pwf  = (const float*)d_in[6];
    const float* pbf  = (const float*)d_in[7];
    float* out = (float*)d_out;
    float* ws  = (float*)d_ws;

    float* bufA = ws + 512;            // NELEM floats
    float* bufB = bufA + NELEM;        // NELEM floats

    prep_kernel<<<dim3(1), dim3(320), 0, stream>>>(kern, pw0, pb0, pw1, pb1, pwf, pbf, ws);

    const dim3 grid(WW/TILEX, HH/TILEY, BATCH);   // (2, 24, 16) = 768 blocks
    const dim3 block(256);

    // T=1 -> 5 RK2 (midpoint) steps, each ONE fused launch.
    step_kernel<<<grid, block, 0, stream>>>(init, bufA, ws);
    step_kernel<<<grid, block, 0, stream>>>(bufA, bufB, ws);
    step_kernel<<<grid, block, 0, stream>>>(bufB, bufA, ws);
    step_kernel<<<grid, block, 0, stream>>>(bufA, bufB, ws);
    step_kernel<<<grid, block, 0, stream>>>(bufB, out,  ws);
}